// Round 1
// baseline (2494.403 us; speedup 1.0000x reference)
//
#include <hip/hip_runtime.h>

#define HID 32
#define NSTEPS 64

// Tiny-MLP evaluator: k = W3^T relu(W2^T relu(W1^T a + b1) + b2) + b3
// All weight accesses use compile-time indices off uniform pointers so the
// backend emits s_load + v_fmac(sgpr) — keeps the inner loop pure VALU.
__device__ __forceinline__ void mlp_eval(
    const float* __restrict__ w1, const float* __restrict__ b1,
    const float* __restrict__ w2, const float* __restrict__ b2,
    const float* __restrict__ w3, const float* __restrict__ b3,
    float a0, float a1, float a2, float* __restrict__ k)
{
    float h1[HID];
#pragma unroll
    for (int j = 0; j < HID; ++j) {
        float v = fmaf(a2, w1[2 * HID + j],
                  fmaf(a1, w1[1 * HID + j],
                  fmaf(a0, w1[0 * HID + j], b1[j])));
        h1[j] = fmaxf(v, 0.0f);
    }
    float h2[HID];
#pragma unroll
    for (int j = 0; j < HID; ++j) h2[j] = b2[j];
#pragma unroll
    for (int i = 0; i < HID; ++i) {
        float hi = h1[i];
#pragma unroll
        for (int j = 0; j < HID; ++j)
            h2[j] = fmaf(hi, w2[i * HID + j], h2[j]);
    }
    float k0 = b3[0], k1 = b3[1], k2 = b3[2];
#pragma unroll
    for (int i = 0; i < HID; ++i) {
        float hi = fmaxf(h2[i], 0.0f);
        k0 = fmaf(hi, w3[i * 3 + 0], k0);
        k1 = fmaf(hi, w3[i * 3 + 1], k1);
        k2 = fmaf(hi, w3[i * 3 + 2], k2);
    }
    k[0] = k0; k[1] = k1; k[2] = k2;
}

__global__ __launch_bounds__(256)
void ode_rk4_kernel(
    const float* __restrict__ x,
    const float* __restrict__ samples,
    const float* __restrict__ w1, const float* __restrict__ b1,
    const float* __restrict__ w2, const float* __restrict__ b2,
    const float* __restrict__ w3, const float* __restrict__ b3,
    const float* __restrict__ w_out, const float* __restrict__ b_out,
    float* __restrict__ out, int B)
{
    const int r = blockIdx.x * blockDim.x + threadIdx.x;
    if (r >= B) return;

    // dt and sample->step indices (all wave-uniform)
    const float maxT = samples[7];           // samples sorted ascending, 8 entries
    const float dt   = maxT / 64.0f;
    const float dt2  = 0.5f * dt;
    const float dt6  = dt / 6.0f;

    int sidx[8];
#pragma unroll
    for (int j = 0; j < 8; ++j) {
        // jnp.round = round-half-even -> rintf in default rounding mode
        int id = (int)rintf(samples[j] / dt) - 1;
        id = id < 0 ? 0 : (id > NSTEPS - 1 ? NSTEPS - 1 : id);
        sidx[j] = id;
    }

    const float wo0 = w_out[0], wo1 = w_out[1], wo2 = w_out[2];
    const float bo  = b_out[0];

    float y0 = x[(size_t)r * 3 + 0];
    float y1 = x[(size_t)r * 3 + 1];
    float y2 = x[(size_t)r * 3 + 2];

#pragma unroll 1
    for (int s = 0; s < NSTEPS; ++s) {
        float acc0 = 0.0f, acc1 = 0.0f, acc2 = 0.0f;
        float a0 = y0, a1 = y1, a2 = y2;
        // RK4: kept rolled (unroll 1) so the hot body is ONE mlp (~11 KB, fits I$)
#pragma unroll 1
        for (int st = 0; st < 4; ++st) {
            float k[3];
            mlp_eval(w1, b1, w2, b2, w3, b3, a0, a1, a2, k);
            const float ca = (st == 1 || st == 2) ? 2.0f : 1.0f;
            acc0 = fmaf(ca, k[0], acc0);
            acc1 = fmaf(ca, k[1], acc1);
            acc2 = fmaf(ca, k[2], acc2);
            const float ci = (st == 2) ? dt : dt2;   // input scale for next stage
            a0 = fmaf(ci, k[0], y0);
            a1 = fmaf(ci, k[1], y1);
            a2 = fmaf(ci, k[2], y2);
        }
        y0 = fmaf(dt6, acc0, y0);
        y1 = fmaf(dt6, acc1, y1);
        y2 = fmaf(dt6, acc2, y2);

        // After completing step s, state == traj[s]; emit any samples mapping here.
#pragma unroll
        for (int j = 0; j < 8; ++j) {
            if (sidx[j] == s) {
                out[(size_t)j * B + r] =
                    fmaf(y2, wo2, fmaf(y1, wo1, fmaf(y0, wo0, bo)));
            }
        }
    }
}

extern "C" void kernel_launch(void* const* d_in, const int* in_sizes, int n_in,
                              void* d_out, int out_size, void* d_ws, size_t ws_size,
                              hipStream_t stream) {
    const float* x       = (const float*)d_in[0];
    const float* samples = (const float*)d_in[1];
    const float* w1      = (const float*)d_in[2];
    const float* b1      = (const float*)d_in[3];
    const float* w2      = (const float*)d_in[4];
    const float* b2      = (const float*)d_in[5];
    const float* w3      = (const float*)d_in[6];
    const float* b3      = (const float*)d_in[7];
    const float* w_out   = (const float*)d_in[8];
    const float* b_out   = (const float*)d_in[9];
    float* out = (float*)d_out;

    const int B = in_sizes[0] / 3;
    const int block = 256;
    const int grid = (B + block - 1) / block;
    ode_rk4_kernel<<<grid, block, 0, stream>>>(
        x, samples, w1, b1, w2, b2, w3, b3, w_out, b_out, out, B);
}